// Round 15
// baseline (4800.583 us; speedup 1.0000x reference)
//
#include <hip/hip_runtime.h>
#include <math.h>
#include <stdint.h>

#define TLEN 512
#define BSZ  64
#define EDIM 256
#define HDIM 256
#define GDIM 1024
#define KTAG 32

__device__ __forceinline__ float sigf(float x) { return 1.0f / (1.0f + expf(-x)); }

// ---------------------------------------------------------------------------
// FUSED kernel. Blocks [0,nlstm): LSTM recurrence for chunk c with 8-block
// clusters (cl = bid&31, rb = bid>>5 in 0..7). Block rb owns 128 W rows
// (units [rb*32, rb*32+32) x 4 gates, 128KB) asm-pinned in registers ->
// per-CU FMA halves vs the 4-block r14 layout (0.43us/step). h exchange:
// STAMPED u64 relaxed agent atomics, 2-slot ring, exact-stamp poll
// (protocol identical to twice-passed r14). Blocks [nlstm,...): next
// chunk's input GEMM (ping-pong), unchanged from r13/r14.
// ---------------------------------------------------------------------------
template<int KDIM, bool GATHER, bool TOXBUF>
__global__ __launch_bounds__(512, 2)
void lstm_fused(
    const float* __restrict__ gx_f, const float* __restrict__ gx_b,
    const float* __restrict__ Wf, const float* __restrict__ Wb,
    float* __restrict__ xout, float* __restrict__ hbuf,
    float* __restrict__ state, uint64_t* __restrict__ hxs,
    unsigned int fbase,
    int t0f, int t0b, int C, int init, int nlstm, int nmt,
    const float* __restrict__ A, const int* __restrict__ idx,
    const float* __restrict__ Bf, const float* __restrict__ Bb,
    const float* __restrict__ b1f, const float* __restrict__ b2f,
    const float* __restrict__ b1b, const float* __restrict__ b2b,
    float* __restrict__ ogx_f, float* __restrict__ ogx_b,
    int gt0f, int gt0b, int gr0f, int gr0b)
{
    __shared__ __align__(16) float h_lds[4][256];
    __shared__ __align__(16) float ps[4][4][128];   // [kq][b][rr]
    __shared__ __align__(16) float gxs[4][128];     // [b][rr]
    __shared__ __align__(16) float As[8][132];
    __shared__ __align__(16) float Bs[8][132];

    const int bid = blockIdx.x;
    const int t = threadIdx.x;

    if (bid < nlstm) {
        // ================= LSTM role (8-block cluster) =================
        const int cl  = bid & 31;
        const int rb  = bid >> 5;          // 0..7 unit-block (32 units)
        const int dir = cl >> 4;
        const int b0g = (cl & 15) * 4;     // first of 4 batch elements
        const float* gx = dir ? gx_b : gx_f;
        const float* W  = dir ? Wb : Wf;
        const int t0 = dir ? t0b : t0f;

        const int rr = t & 127;            // row-in-block: g = rr>>5, ul = rr&31
        const int kq = t >> 7;             // k-quarter 0..3 (64 k each)
        const int urow = ((rr >> 5) * 256) + rb * 32 + (rr & 31);

        float4 w[16];
        {
            const float4* wrow = (const float4*)(W + (size_t)urow * HDIM + kq * 64);
            #pragma unroll
            for (int i = 0; i < 16; ++i) w[i] = wrow[i];
        }
        #pragma unroll
        for (int i = 0; i < 16; ++i)
            asm volatile("" : "+v"(w[i].x), "+v"(w[i].y), "+v"(w[i].z), "+v"(w[i].w));

        float cc = 0.0f;
        for (int i = t; i < 4 * 256; i += 512) {
            int b = i >> 8, u = i & 255;
            h_lds[b][u] = init ? 0.0f
                : state[(((size_t)dir * BSZ + (b0g + b)) * 2) * HDIM + u];
        }
        if (t < 128) {
            int b = t >> 5, ug = rb * 32 + (t & 31);
            if (!init)
                cc = state[(((size_t)dir * BSZ + (b0g + b)) * 2) * HDIM + HDIM + ug];
        }
        __syncthreads();
        __builtin_amdgcn_s_setprio(1);

        for (int s = 0; s < C; ++s) {
            const int tloc = dir ? (C - 1 - s) : s;
            // gx prefetch: 512 values, 1 per thread (own rows only)
            const int pb = t >> 7;         // batch 0..3
            float gv = gx[((size_t)tloc * BSZ + (b0g + pb)) * GDIM + urow];
            // FMA: own 128 rows x 4 batch over k-quarter (in registers)
            float a0 = 0.f, a1 = 0.f, a2 = 0.f, a3 = 0.f;
            #pragma unroll
            for (int i = 0; i < 16; ++i) {
                float4 h0 = *(const float4*)&h_lds[0][kq * 64 + i * 4];
                float4 h1 = *(const float4*)&h_lds[1][kq * 64 + i * 4];
                float4 h2 = *(const float4*)&h_lds[2][kq * 64 + i * 4];
                float4 h3 = *(const float4*)&h_lds[3][kq * 64 + i * 4];
                a0 = fmaf(w[i].x, h0.x, a0); a0 = fmaf(w[i].y, h0.y, a0);
                a0 = fmaf(w[i].z, h0.z, a0); a0 = fmaf(w[i].w, h0.w, a0);
                a1 = fmaf(w[i].x, h1.x, a1); a1 = fmaf(w[i].y, h1.y, a1);
                a1 = fmaf(w[i].z, h1.z, a1); a1 = fmaf(w[i].w, h1.w, a1);
                a2 = fmaf(w[i].x, h2.x, a2); a2 = fmaf(w[i].y, h2.y, a2);
                a2 = fmaf(w[i].z, h2.z, a2); a2 = fmaf(w[i].w, h2.w, a2);
                a3 = fmaf(w[i].x, h3.x, a3); a3 = fmaf(w[i].y, h3.y, a3);
                a3 = fmaf(w[i].z, h3.z, a3); a3 = fmaf(w[i].w, h3.w, a3);
            }
            ps[kq][0][rr] = a0; ps[kq][1][rr] = a1;
            ps[kq][2][rr] = a2; ps[kq][3][rr] = a3;
            gxs[pb][rr] = gv;
            __syncthreads();
            const unsigned want = fbase + (unsigned)(s + 1);
            if (t < 128) {
                const int b = t >> 5, ul = t & 31;
                float pi = ps[0][b][ul]      + ps[1][b][ul]      + ps[2][b][ul]      + ps[3][b][ul]      + gxs[b][ul];
                float pf = ps[0][b][32 + ul] + ps[1][b][32 + ul] + ps[2][b][32 + ul] + ps[3][b][32 + ul] + gxs[b][32 + ul];
                float pg = ps[0][b][64 + ul] + ps[1][b][64 + ul] + ps[2][b][64 + ul] + ps[3][b][64 + ul] + gxs[b][64 + ul];
                float po = ps[0][b][96 + ul] + ps[1][b][96 + ul] + ps[2][b][96 + ul] + ps[3][b][96 + ul] + gxs[b][96 + ul];
                float iv = sigf(pi), fv = sigf(pf), gv2 = tanhf(pg), ov = sigf(po);
                cc = fv * cc + iv * gv2;
                float hv = ov * tanhf(cc);
                const int ug = rb * 32 + ul;
                h_lds[b][ug] = hv;
                uint64_t pv = ((uint64_t)want << 32) | (uint64_t)__float_as_uint(hv);
                __hip_atomic_store(&hxs[(((size_t)(s & 1) * 32 + cl) * 4 + b) * 256 + ug],
                                   pv, __ATOMIC_RELAXED, __HIP_MEMORY_SCOPE_AGENT);
                // off the critical chain:
                if (TOXBUF)
                    xout[((size_t)(t0 + tloc) * BSZ + (b0g + b)) * 512 + dir * HDIM + ug] = hv;
                else
                    hbuf[(((size_t)dir * C + tloc) * BSZ + (b0g + b)) * HDIM + ug] = hv;
            }
            // poll siblings' 896 h values directly (exact stamp)
            __builtin_amdgcn_s_setprio(0);
            #pragma unroll
            for (int q = 0; q < 2; ++q) {
                int i = t + q * 512;
                int b = i >> 8, u = i & 255;
                if ((u >> 5) != rb) {
                    const uint64_t* src =
                        &hxs[(((size_t)(s & 1) * 32 + cl) * 4 + b) * 256 + u];
                    uint64_t v;
                    do {
                        v = __hip_atomic_load(src, __ATOMIC_RELAXED,
                                              __HIP_MEMORY_SCOPE_AGENT);
                    } while ((unsigned)(v >> 32) != want);
                    h_lds[b][u] = __uint_as_float((unsigned)v);
                }
            }
            __builtin_amdgcn_s_setprio(1);
            __syncthreads();
        }
        __builtin_amdgcn_s_setprio(0);
        if (t < 128) {
            int b = t >> 5, ug = rb * 32 + (t & 31);
            size_t sb = (((size_t)dir * BSZ + (b0g + b)) * 2) * HDIM;
            state[sb + ug] = h_lds[b][ug];
            state[sb + HDIM + ug] = cc;
        }
        return;
    }

    // ================= GEMM role: next chunk's gx (128x128 tile) ===========
    const int g = bid - nlstm;
    const int mx = g % nmt;
    const int ny = g / nmt;
    const int mt = mx * 128;
    const int ngc = ny * 128;
    const bool isF = (ngc < GDIM);
    const int nt = isF ? ngc : (ngc - GDIM);
    const float* Bw = isF ? Bf : Bb;
    const float* bias1 = isF ? b1f : b1b;
    const float* bias2 = isF ? b2f : b2b;
    float* Cc = isF ? ogx_f : ogx_b;
    const int t0 = isF ? gt0f : gt0b;
    const int r0 = isF ? gr0f : gr0b;

    const int tx = t & 15;
    const int ty = t >> 4;        // 0..31 -> rows ty*4..ty*4+3
    const int l_row = t >> 2;     // 0..127
    const int l_k = (t & 3) * 2;  // k-pair 0,2,4,6

    const float* arow;
    if (GATHER) {
        int m = mt + l_row;
        int tt = t0 + (m >> 6);
        int b = m & 63;
        arow = A + (size_t)idx[b * TLEN + tt] * (size_t)KDIM;
    } else {
        arow = A + (size_t)(r0 + mt + l_row) * (size_t)KDIM;
    }
    const float* brow = Bw + (size_t)(nt + l_row) * (size_t)KDIM;

    float acc[4][8];
    #pragma unroll
    for (int i = 0; i < 4; ++i)
        #pragma unroll
        for (int j = 0; j < 8; ++j) acc[i][j] = 0.0f;

    float2 av = *(const float2*)(arow + l_k);
    float2 bv = *(const float2*)(brow + l_k);
    for (int k0 = 0; k0 < KDIM; k0 += 8) {
        __syncthreads();
        As[l_k + 0][l_row] = av.x; As[l_k + 1][l_row] = av.y;
        Bs[l_k + 0][l_row] = bv.x; Bs[l_k + 1][l_row] = bv.y;
        __syncthreads();
        if (k0 + 8 < KDIM) {   // prefetch next panel under the compute
            av = *(const float2*)(arow + k0 + 8 + l_k);
            bv = *(const float2*)(brow + k0 + 8 + l_k);
        }
        #pragma unroll
        for (int k = 0; k < 8; ++k) {
            float a[4], bb2[8];
            *(float4*)(a)       = *(const float4*)&As[k][ty * 4];
            *(float4*)(bb2)     = *(const float4*)&Bs[k][tx * 4];
            *(float4*)(bb2 + 4) = *(const float4*)&Bs[k][64 + tx * 4];
            #pragma unroll
            for (int i = 0; i < 4; ++i)
                #pragma unroll
                for (int j = 0; j < 8; ++j)
                    acc[i][j] = fmaf(a[i], bb2[j], acc[i][j]);
        }
    }

    float bs[8];
    #pragma unroll
    for (int j = 0; j < 4; ++j) bs[j] = bias1[nt + tx * 4 + j] + bias2[nt + tx * 4 + j];
    #pragma unroll
    for (int j = 4; j < 8; ++j) bs[j] = bias1[nt + 64 + tx * 4 + j - 4] + bias2[nt + 64 + tx * 4 + j - 4];
    #pragma unroll
    for (int i = 0; i < 4; ++i) {
        size_t row = (size_t)(mt + ty * 4 + i);
        float* cp0 = Cc + row * GDIM + nt + tx * 4;
        float* cp1 = Cc + row * GDIM + nt + 64 + tx * 4;
        *(float4*)cp0 = make_float4(acc[i][0] + bs[0], acc[i][1] + bs[1],
                                    acc[i][2] + bs[2], acc[i][3] + bs[3]);
        *(float4*)cp1 = make_float4(acc[i][4] + bs[4], acc[i][5] + bs[5],
                                    acc[i][6] + bs[6], acc[i][7] + bs[7]);
    }
}

// ---------------------------------------------------------------------------
// Partial emissions from one chunk of layer-1 h (both dirs).
// ---------------------------------------------------------------------------
__global__ __launch_bounds__(256)
void emis_part(const float* __restrict__ hbuf, const float* __restrict__ Wo,
               float* __restrict__ em_f, float* __restrict__ em_b,
               int t0f, int t0b, int C)
{
    __shared__ float Ws[128][33];
    const int dir = blockIdx.y;
    const int tid = threadIdx.x;
    const int r = tid >> 5;
    const int kk = tid & 31;
    const int mloc = blockIdx.x * 8 + r;
    const float* hrow = hbuf + ((size_t)dir * C * BSZ + mloc) * HDIM;
    float* emo = dir ? em_b : em_f;
    const int t0 = dir ? t0b : t0f;
    float acc = 0.0f;
    for (int kc = 0; kc < HDIM; kc += 128) {
        __syncthreads();
        for (int i = tid; i < KTAG * 128; i += 256) {
            int wk = i >> 7;
            int k = i & 127;
            Ws[k][wk] = Wo[(size_t)wk * 512 + dir * HDIM + kc + k];
        }
        __syncthreads();
        #pragma unroll 8
        for (int k4 = 0; k4 < 32; ++k4) {
            float4 xv = *(const float4*)(hrow + kc + k4 * 4);
            acc = fmaf(xv.x, Ws[k4 * 4 + 0][kk], acc);
            acc = fmaf(xv.y, Ws[k4 * 4 + 1][kk], acc);
            acc = fmaf(xv.z, Ws[k4 * 4 + 2][kk], acc);
            acc = fmaf(xv.w, Ws[k4 * 4 + 3][kk], acc);
        }
    }
    const int tloc = mloc >> 6;
    const int b = mloc & 63;
    emo[(((size_t)(t0 + tloc)) * BSZ + b) * KTAG + kk] = acc;
}

// ---------------------------------------------------------------------------
// Viterbi: one block per batch element; em prefetch + LDS backpointers.
// ---------------------------------------------------------------------------
__global__ __launch_bounds__(64)
void viterbi(const float* __restrict__ em_f, const float* __restrict__ em_b,
             const float* __restrict__ bo,
             const float* __restrict__ st, const float* __restrict__ en,
             const float* __restrict__ tr, int* __restrict__ out)
{
    const int b = blockIdx.x;
    const int lane = threadIdx.x;
    __shared__ float s_tr[KTAG][KTAG + 1];
    __shared__ float s_sc[KTAG];
    __shared__ float s_fin[KTAG];
    __shared__ unsigned char s_bp[TLEN - 1][KTAG];
    for (int i = lane; i < KTAG * KTAG; i += 64)
        s_tr[i >> 5][i & 31] = tr[i];
    float eFn = 0.f, eBn = 0.f;
    if (lane < KTAG) {
        size_t e0 = (size_t)b * KTAG + lane;
        s_sc[lane] = st[lane] + em_f[e0] + em_b[e0] + bo[lane];
        size_t e1 = ((size_t)1 * BSZ + b) * KTAG + lane;
        eFn = em_f[e1]; eBn = em_b[e1];
    }
    __syncthreads();
    for (int t = 1; t < TLEN; ++t) {
        float ecF = eFn, ecB = eBn;
        if (t + 1 < TLEN && lane < KTAG) {
            size_t e2 = ((size_t)(t + 1) * BSZ + b) * KTAG + lane;
            eFn = em_f[e2]; eBn = em_b[e2];
        }
        float best = -3.0e38f;
        int arg = 0;
        if (lane < KTAG) {
            #pragma unroll
            for (int i = 0; i < KTAG; ++i) {
                float c = s_sc[i] + s_tr[i][lane];
                if (c > best) { best = c; arg = i; }
            }
        }
        __syncthreads();
        if (lane < KTAG) {
            s_sc[lane] = best + ecF + ecB + bo[lane];
            s_bp[t - 1][lane] = (unsigned char)arg;
        }
        __syncthreads();
    }
    if (lane < KTAG) s_fin[lane] = s_sc[lane] + en[lane];
    __syncthreads();
    if (lane == 0) {
        int tag = 0;
        float bv = s_fin[0];
        for (int i = 1; i < KTAG; ++i)
            if (s_fin[i] > bv) { bv = s_fin[i]; tag = i; }
        out[(size_t)b * TLEN + (TLEN - 1)] = tag;
        for (int t = TLEN - 2; t >= 0; --t) {
            tag = s_bp[t][tag];
            out[(size_t)b * TLEN + t] = tag;
        }
    }
}

// ---------------------------------------------------------------------------
extern "C" void kernel_launch(void* const* d_in, const int* in_sizes, int n_in,
                              void* d_out, int out_size, void* d_ws, size_t ws_size,
                              hipStream_t stream)
{
    (void)in_sizes; (void)n_in; (void)out_size;
    const int*   inputs     = (const int*)d_in[0];
    const float* emb        = (const float*)d_in[1];
    const float* W_ih_l0_f  = (const float*)d_in[2];
    const float* W_hh_l0_f  = (const float*)d_in[3];
    const float* b_ih_l0_f  = (const float*)d_in[4];
    const float* b_hh_l0_f  = (const float*)d_in[5];
    const float* W_ih_l0_b  = (const float*)d_in[6];
    const float* W_hh_l0_b  = (const float*)d_in[7];
    const float* b_ih_l0_b  = (const float*)d_in[8];
    const float* b_hh_l0_b  = (const float*)d_in[9];
    const float* W_ih_l1_f  = (const float*)d_in[10];
    const float* W_hh_l1_f  = (const float*)d_in[11];
    const float* b_ih_l1_f  = (const float*)d_in[12];
    const float* b_hh_l1_f  = (const float*)d_in[13];
    const float* W_ih_l1_b  = (const float*)d_in[14];
    const float* W_hh_l1_b  = (const float*)d_in[15];
    const float* b_ih_l1_b  = (const float*)d_in[16];
    const float* b_hh_l1_b  = (const float*)d_in[17];
    const float* W_out      = (const float*)d_in[18];
    const float* b_out      = (const float*)d_in[19];
    const float* start_tr   = (const float*)d_in[20];
    const float* end_tr     = (const float*)d_in[21];
    const float* trans      = (const float*)d_in[22];

    // ws: xbuf 64MB | gxA_f gxA_b gxB_f gxB_b (4 x C*256KB) | hbuf C*128KB |
    //     em_f 4MB | em_b 4MB | state 512KB | hxs 512KB
    const size_t XBUF = 67108864ull;
    const size_t PERC = 4ull * 262144 + 131072;          // 1.125 MB per C
    const size_t TAIL = 2ull * 4194304 + 524288 + 524288;
    int C = 8;
    for (int cand = TLEN; cand >= 8; cand >>= 1) {
        if (XBUF + (size_t)cand * PERC + TAIL <= ws_size) { C = cand; break; }
    }
    char* ws = (char*)d_ws;
    float* xbuf  = (float*)(ws);
    char*  p     = ws + XBUF;
    float* gxA_f = (float*)(p); p += (size_t)C * 262144;
    float* gxA_b = (float*)(p); p += (size_t)C * 262144;
    float* gxB_f = (float*)(p); p += (size_t)C * 262144;
    float* gxB_b = (float*)(p); p += (size_t)C * 262144;
    float* hbuf  = (float*)(p); p += (size_t)C * 131072;
    float* em_f  = (float*)(p); p += 4194304;
    float* em_b  = (float*)(p); p += 4194304;
    float* state = (float*)(p); p += 524288;
    uint64_t* hxs = (uint64_t*)(p);
    int* outi = (int*)d_out;

    const int nc = TLEN / C;
    const int nmt = C / 2;          // 128-row m-tiles per chunk
    const int NG = nmt * 16;        // gemm blocks (both dirs)
    const int NL = 256;             // lstm blocks (8 per cluster x 32)
    float* gxf[2] = { gxA_f, gxB_f };
    float* gxb[2] = { gxA_b, gxB_b };

    hipMemsetAsync(hxs, 0, 524288, stream);   // stamp 0 everywhere
    unsigned fbase = 0;

    // ----- layer 0 ----- (warmup gemm chunk 0, then fused chain)
    lstm_fused<EDIM, true, true><<<NG, 512, 0, stream>>>(
        gxA_f, gxA_b, W_hh_l0_f, W_hh_l0_b, xbuf, nullptr, state, hxs, 0,
        0, 0, C, 1, /*nlstm=*/0, nmt,
        emb, inputs, W_ih_l0_f, W_ih_l0_b,
        b_ih_l0_f, b_hh_l0_f, b_ih_l0_b, b_hh_l0_b,
        gxA_f, gxA_b, 0, TLEN - C, 0, 0);
    for (int c = 0; c < nc; ++c) {
        int cur = c & 1, nxt = cur ^ 1;
        int hasN = (c + 1 < nc);
        int t0f = c * C, t0b = TLEN - (c + 1) * C;
        int g0f = (c + 1) * C, g0b = TLEN - (c + 2) * C;
        lstm_fused<EDIM, true, true><<<NL + (hasN ? NG : 0), 512, 0, stream>>>(
            gxf[cur], gxb[cur], W_hh_l0_f, W_hh_l0_b, xbuf, nullptr, state,
            hxs, fbase, t0f, t0b, C, c == 0 ? 1 : 0, NL, nmt,
            emb, inputs, W_ih_l0_f, W_ih_l0_b,
            b_ih_l0_f, b_hh_l0_f, b_ih_l0_b, b_hh_l0_b,
            gxf[nxt], gxb[nxt], g0f, g0b, 0, 0);
        fbase += (unsigned)C;
    }
    // ----- layer 1 ----- (xbuf READ-ONLY; h -> hbuf -> em parts)
    lstm_fused<512, false, false><<<NG, 512, 0, stream>>>(
        gxA_f, gxA_b, W_hh_l1_f, W_hh_l1_b, nullptr, hbuf, state, hxs, 0,
        0, 0, C, 1, /*nlstm=*/0, nmt,
        xbuf, nullptr, W_ih_l1_f, W_ih_l1_b,
        b_ih_l1_f, b_hh_l1_f, b_ih_l1_b, b_hh_l1_b,
        gxA_f, gxA_b, 0, TLEN - C, 0, (TLEN - C) * BSZ);
    for (int c = 0; c < nc; ++c) {
        int cur = c & 1, nxt = cur ^ 1;
        int hasN = (c + 1 < nc);
        int t0f = c * C, t0b = TLEN - (c + 1) * C;
        int g0f = (c + 1) * C, g0b = TLEN - (c + 2) * C;
        lstm_fused<512, false, false><<<NL + (hasN ? NG : 0), 512, 0, stream>>>(
            gxf[cur], gxb[cur], W_hh_l1_f, W_hh_l1_b, nullptr, hbuf, state,
            hxs, fbase, t0f, t0b, C, c == 0 ? 1 : 0, NL, nmt,
            xbuf, nullptr, W_ih_l1_f, W_ih_l1_b,
            b_ih_l1_f, b_hh_l1_f, b_ih_l1_b, b_hh_l1_b,
            gxf[nxt], gxb[nxt], g0f, g0b, g0f * BSZ, g0b * BSZ);
        fbase += (unsigned)C;
        dim3 ge(C * 8, 2);
        emis_part<<<ge, 256, 0, stream>>>(hbuf, W_out, em_f, em_b, t0f, t0b, C);
    }

    viterbi<<<64, 64, 0, stream>>>(em_f, em_b, b_out, start_tr, end_tr, trans,
                                   outi);
}

// Round 16
// 4246.938 us; speedup vs baseline: 1.1304x; 1.1304x over previous
//
#include <hip/hip_runtime.h>
#include <math.h>
#include <stdint.h>

#define TLEN 512
#define BSZ  64
#define EDIM 256
#define HDIM 256
#define GDIM 1024
#define KTAG 32

__device__ __forceinline__ float sigf(float x) { return 1.0f / (1.0f + expf(-x)); }

// ---------------------------------------------------------------------------
// FUSED kernel. Blocks [0,nlstm): LSTM recurrence, 64 clusters x 4 blocks
// (cl = bid&63, rb = bid>>6). Cluster handles (dir = cl>>5, batch pair
// b0g = (cl&31)*2). Block rb owns 256 W rows (units [rb*64,rb*64+64) x 4
// gates, 256KB) asm-pinned in registers. Exchange: STAMPED u64 relaxed
// agent atomics, 2-slot ring, exact-stamp poll (r14-proven protocol,
// 4 parties). gx(s+1) prefetch issued BETWEEN publish and poll so the
// ~600cy load fills the stamp-propagation window (fewer poll retries).
// Blocks [nlstm,...): next chunk's input GEMM (ping-pong), r13/r14 code.
// ---------------------------------------------------------------------------
template<int KDIM, bool GATHER, bool TOXBUF>
__global__ __launch_bounds__(512, 2)
void lstm_fused(
    const float* __restrict__ gx_f, const float* __restrict__ gx_b,
    const float* __restrict__ Wf, const float* __restrict__ Wb,
    float* __restrict__ xout, float* __restrict__ hbuf,
    float* __restrict__ state, uint64_t* __restrict__ hxs,
    unsigned int fbase,
    int t0f, int t0b, int C, int init, int nlstm, int nmt,
    const float* __restrict__ A, const int* __restrict__ idx,
    const float* __restrict__ Bf, const float* __restrict__ Bb,
    const float* __restrict__ b1f, const float* __restrict__ b2f,
    const float* __restrict__ b1b, const float* __restrict__ b2b,
    float* __restrict__ ogx_f, float* __restrict__ ogx_b,
    int gt0f, int gt0b, int gr0f, int gr0b)
{
    __shared__ __align__(16) float h_lds[2][256];
    __shared__ __align__(16) float ps[2][2][256];   // [kh][b][rr]
    __shared__ __align__(16) float gxs[2][256];     // [b][rr]
    __shared__ __align__(16) float As[8][132];
    __shared__ __align__(16) float Bs[8][132];

    const int bid = blockIdx.x;
    const int t = threadIdx.x;

    if (bid < nlstm) {
        // ================= LSTM role (4-block cluster, 2 batch) ============
        const int cl  = bid & 63;
        const int rb  = bid >> 6;          // 0..3 unit-block (64 units)
        const int dir = cl >> 5;
        const int b0g = (cl & 31) * 2;     // first of 2 batch elements
        const float* gx = dir ? gx_b : gx_f;
        const float* W  = dir ? Wb : Wf;
        const int t0 = dir ? t0b : t0f;

        const int rr = t & 255;            // W row in block: g = rr>>6, ul = rr&63
        const int kh = t >> 8;             // k-half (128 k each)
        const int urow = ((rr >> 6) * 256) + rb * 64 + (rr & 63);

        float4 w[32];
        {
            const float4* wrow = (const float4*)(W + (size_t)urow * HDIM + kh * 128);
            #pragma unroll
            for (int i = 0; i < 32; ++i) w[i] = wrow[i];
        }
        #pragma unroll
        for (int i = 0; i < 32; ++i)
            asm volatile("" : "+v"(w[i].x), "+v"(w[i].y), "+v"(w[i].z), "+v"(w[i].w));

        float cc = 0.0f;
        for (int i = t; i < 2 * 256; i += 512) {
            int b = i >> 8, u = i & 255;
            h_lds[b][u] = init ? 0.0f
                : state[(((size_t)dir * BSZ + (b0g + b)) * 2) * HDIM + u];
        }
        if (t < 128) {
            int b = t >> 6, ug = rb * 64 + (t & 63);
            if (!init)
                cc = state[(((size_t)dir * BSZ + (b0g + b)) * 2) * HDIM + HDIM + ug];
        }
        __syncthreads();
        __builtin_amdgcn_s_setprio(1);

        // prologue gx load for s=0 (1 value/thread: batch pb, row rr)
        const int pb = t >> 8;
        {
            const int tl0 = dir ? (C - 1) : 0;
            // nothing else
        }
        float gv = gx[((size_t)(dir ? (C - 1) : 0) * BSZ + (b0g + pb)) * GDIM + urow];

        for (int s = 0; s < C; ++s) {
            const int tloc = dir ? (C - 1 - s) : s;
            // ---- FMA: own 256 rows x 2 batch over k-half (in registers) ----
            float a0 = 0.f, a1 = 0.f;
            #pragma unroll
            for (int i = 0; i < 32; ++i) {
                float4 h0 = *(const float4*)&h_lds[0][kh * 128 + i * 4];
                float4 h1 = *(const float4*)&h_lds[1][kh * 128 + i * 4];
                a0 = fmaf(w[i].x, h0.x, a0); a0 = fmaf(w[i].y, h0.y, a0);
                a0 = fmaf(w[i].z, h0.z, a0); a0 = fmaf(w[i].w, h0.w, a0);
                a1 = fmaf(w[i].x, h1.x, a1); a1 = fmaf(w[i].y, h1.y, a1);
                a1 = fmaf(w[i].z, h1.z, a1); a1 = fmaf(w[i].w, h1.w, a1);
            }
            ps[kh][0][rr] = a0; ps[kh][1][rr] = a1;
            gxs[pb][rr] = gv;
            __syncthreads();
            const unsigned want = fbase + (unsigned)(s + 1);
            if (t < 128) {
                const int b = t >> 6, ul = t & 63;
                float pi = ps[0][b][ul]       + ps[1][b][ul]       + gxs[b][ul];
                float pf = ps[0][b][64 + ul]  + ps[1][b][64 + ul]  + gxs[b][64 + ul];
                float pg = ps[0][b][128 + ul] + ps[1][b][128 + ul] + gxs[b][128 + ul];
                float po = ps[0][b][192 + ul] + ps[1][b][192 + ul] + gxs[b][192 + ul];
                float iv = sigf(pi), fv = sigf(pf), gv2 = tanhf(pg), ov = sigf(po);
                cc = fv * cc + iv * gv2;
                float hv = ov * tanhf(cc);
                const int ug = rb * 64 + ul;
                h_lds[b][ug] = hv;
                uint64_t pv = ((uint64_t)want << 32) | (uint64_t)__float_as_uint(hv);
                __hip_atomic_store(&hxs[(((size_t)(s & 1) * 64 + cl) * 2 + b) * 256 + ug],
                                   pv, __ATOMIC_RELAXED, __HIP_MEMORY_SCOPE_AGENT);
                // off the critical chain:
                if (TOXBUF)
                    xout[((size_t)(t0 + tloc) * BSZ + (b0g + b)) * 512 + dir * HDIM + ug] = hv;
                else
                    hbuf[(((size_t)dir * C + tloc) * BSZ + (b0g + b)) * HDIM + ug] = hv;
            }
            // ---- prefetch gx for s+1 (fills the stamp-propagation window) --
            if (s + 1 < C) {
                const int tl2 = dir ? (C - 2 - s) : (s + 1);
                gv = gx[((size_t)tl2 * BSZ + (b0g + pb)) * GDIM + urow];
            }
            // ---- poll siblings' 384 h values (exact stamp) ----
            __builtin_amdgcn_s_setprio(0);
            if (t < 384) {
                const int b = t / 192;
                const int ix = t % 192;
                const int u = (ix < rb * 64) ? ix : ix + 64;   // skip own 64
                const uint64_t* src =
                    &hxs[(((size_t)(s & 1) * 64 + cl) * 2 + b) * 256 + u];
                uint64_t v;
                do {
                    v = __hip_atomic_load(src, __ATOMIC_RELAXED,
                                          __HIP_MEMORY_SCOPE_AGENT);
                } while ((unsigned)(v >> 32) != want);
                h_lds[b][u] = __uint_as_float((unsigned)v);
            }
            __builtin_amdgcn_s_setprio(1);
            __syncthreads();
        }
        __builtin_amdgcn_s_setprio(0);
        if (t < 128) {
            int b = t >> 6, ug = rb * 64 + (t & 63);
            size_t sb = (((size_t)dir * BSZ + (b0g + b)) * 2) * HDIM;
            state[sb + ug] = h_lds[b][ug];
            state[sb + HDIM + ug] = cc;
        }
        return;
    }

    // ================= GEMM role: next chunk's gx (128x128 tile) ===========
    const int g = bid - nlstm;
    const int mx = g % nmt;
    const int ny = g / nmt;
    const int mt = mx * 128;
    const int ngc = ny * 128;
    const bool isF = (ngc < GDIM);
    const int nt = isF ? ngc : (ngc - GDIM);
    const float* Bw = isF ? Bf : Bb;
    const float* bias1 = isF ? b1f : b1b;
    const float* bias2 = isF ? b2f : b2b;
    float* Cc = isF ? ogx_f : ogx_b;
    const int t0 = isF ? gt0f : gt0b;
    const int r0 = isF ? gr0f : gr0b;

    const int tx = t & 15;
    const int ty = t >> 4;        // 0..31 -> rows ty*4..ty*4+3
    const int l_row = t >> 2;     // 0..127
    const int l_k = (t & 3) * 2;  // k-pair 0,2,4,6

    const float* arow;
    if (GATHER) {
        int m = mt + l_row;
        int tt = t0 + (m >> 6);
        int b = m & 63;
        arow = A + (size_t)idx[b * TLEN + tt] * (size_t)KDIM;
    } else {
        arow = A + (size_t)(r0 + mt + l_row) * (size_t)KDIM;
    }
    const float* brow = Bw + (size_t)(nt + l_row) * (size_t)KDIM;

    float acc[4][8];
    #pragma unroll
    for (int i = 0; i < 4; ++i)
        #pragma unroll
        for (int j = 0; j < 8; ++j) acc[i][j] = 0.0f;

    float2 av = *(const float2*)(arow + l_k);
    float2 bv = *(const float2*)(brow + l_k);
    for (int k0 = 0; k0 < KDIM; k0 += 8) {
        __syncthreads();
        As[l_k + 0][l_row] = av.x; As[l_k + 1][l_row] = av.y;
        Bs[l_k + 0][l_row] = bv.x; Bs[l_k + 1][l_row] = bv.y;
        __syncthreads();
        if (k0 + 8 < KDIM) {   // prefetch next panel under the compute
            av = *(const float2*)(arow + k0 + 8 + l_k);
            bv = *(const float2*)(brow + k0 + 8 + l_k);
        }
        #pragma unroll
        for (int k = 0; k < 8; ++k) {
            float a[4], bb2[8];
            *(float4*)(a)       = *(const float4*)&As[k][ty * 4];
            *(float4*)(bb2)     = *(const float4*)&Bs[k][tx * 4];
            *(float4*)(bb2 + 4) = *(const float4*)&Bs[k][64 + tx * 4];
            #pragma unroll
            for (int i = 0; i < 4; ++i)
                #pragma unroll
                for (int j = 0; j < 8; ++j)
                    acc[i][j] = fmaf(a[i], bb2[j], acc[i][j]);
        }
    }

    float bs[8];
    #pragma unroll
    for (int j = 0; j < 4; ++j) bs[j] = bias1[nt + tx * 4 + j] + bias2[nt + tx * 4 + j];
    #pragma unroll
    for (int j = 4; j < 8; ++j) bs[j] = bias1[nt + 64 + tx * 4 + j - 4] + bias2[nt + 64 + tx * 4 + j - 4];
    #pragma unroll
    for (int i = 0; i < 4; ++i) {
        size_t row = (size_t)(mt + ty * 4 + i);
        float* cp0 = Cc + row * GDIM + nt + tx * 4;
        float* cp1 = Cc + row * GDIM + nt + 64 + tx * 4;
        *(float4*)cp0 = make_float4(acc[i][0] + bs[0], acc[i][1] + bs[1],
                                    acc[i][2] + bs[2], acc[i][3] + bs[3]);
        *(float4*)cp1 = make_float4(acc[i][4] + bs[4], acc[i][5] + bs[5],
                                    acc[i][6] + bs[6], acc[i][7] + bs[7]);
    }
}

// ---------------------------------------------------------------------------
// Partial emissions from one chunk of layer-1 h (both dirs).
// ---------------------------------------------------------------------------
__global__ __launch_bounds__(256)
void emis_part(const float* __restrict__ hbuf, const float* __restrict__ Wo,
               float* __restrict__ em_f, float* __restrict__ em_b,
               int t0f, int t0b, int C)
{
    __shared__ float Ws[128][33];
    const int dir = blockIdx.y;
    const int tid = threadIdx.x;
    const int r = tid >> 5;
    const int kk = tid & 31;
    const int mloc = blockIdx.x * 8 + r;
    const float* hrow = hbuf + ((size_t)dir * C * BSZ + mloc) * HDIM;
    float* emo = dir ? em_b : em_f;
    const int t0 = dir ? t0b : t0f;
    float acc = 0.0f;
    for (int kc = 0; kc < HDIM; kc += 128) {
        __syncthreads();
        for (int i = tid; i < KTAG * 128; i += 256) {
            int wk = i >> 7;
            int k = i & 127;
            Ws[k][wk] = Wo[(size_t)wk * 512 + dir * HDIM + kc + k];
        }
        __syncthreads();
        #pragma unroll 8
        for (int k4 = 0; k4 < 32; ++k4) {
            float4 xv = *(const float4*)(hrow + kc + k4 * 4);
            acc = fmaf(xv.x, Ws[k4 * 4 + 0][kk], acc);
            acc = fmaf(xv.y, Ws[k4 * 4 + 1][kk], acc);
            acc = fmaf(xv.z, Ws[k4 * 4 + 2][kk], acc);
            acc = fmaf(xv.w, Ws[k4 * 4 + 3][kk], acc);
        }
    }
    const int tloc = mloc >> 6;
    const int b = mloc & 63;
    emo[(((size_t)(t0 + tloc)) * BSZ + b) * KTAG + kk] = acc;
}

// ---------------------------------------------------------------------------
// Viterbi: one block per batch element; em prefetch + LDS backpointers.
// ---------------------------------------------------------------------------
__global__ __launch_bounds__(64)
void viterbi(const float* __restrict__ em_f, const float* __restrict__ em_b,
             const float* __restrict__ bo,
             const float* __restrict__ st, const float* __restrict__ en,
             const float* __restrict__ tr, int* __restrict__ out)
{
    const int b = blockIdx.x;
    const int lane = threadIdx.x;
    __shared__ float s_tr[KTAG][KTAG + 1];
    __shared__ float s_sc[KTAG];
    __shared__ float s_fin[KTAG];
    __shared__ unsigned char s_bp[TLEN - 1][KTAG];
    for (int i = lane; i < KTAG * KTAG; i += 64)
        s_tr[i >> 5][i & 31] = tr[i];
    float eFn = 0.f, eBn = 0.f;
    if (lane < KTAG) {
        size_t e0 = (size_t)b * KTAG + lane;
        s_sc[lane] = st[lane] + em_f[e0] + em_b[e0] + bo[lane];
        size_t e1 = ((size_t)1 * BSZ + b) * KTAG + lane;
        eFn = em_f[e1]; eBn = em_b[e1];
    }
    __syncthreads();
    for (int t = 1; t < TLEN; ++t) {
        float ecF = eFn, ecB = eBn;
        if (t + 1 < TLEN && lane < KTAG) {
            size_t e2 = ((size_t)(t + 1) * BSZ + b) * KTAG + lane;
            eFn = em_f[e2]; eBn = em_b[e2];
        }
        float best = -3.0e38f;
        int arg = 0;
        if (lane < KTAG) {
            #pragma unroll
            for (int i = 0; i < KTAG; ++i) {
                float c = s_sc[i] + s_tr[i][lane];
                if (c > best) { best = c; arg = i; }
            }
        }
        __syncthreads();
        if (lane < KTAG) {
            s_sc[lane] = best + ecF + ecB + bo[lane];
            s_bp[t - 1][lane] = (unsigned char)arg;
        }
        __syncthreads();
    }
    if (lane < KTAG) s_fin[lane] = s_sc[lane] + en[lane];
    __syncthreads();
    if (lane == 0) {
        int tag = 0;
        float bv = s_fin[0];
        for (int i = 1; i < KTAG; ++i)
            if (s_fin[i] > bv) { bv = s_fin[i]; tag = i; }
        out[(size_t)b * TLEN + (TLEN - 1)] = tag;
        for (int t = TLEN - 2; t >= 0; --t) {
            tag = s_bp[t][tag];
            out[(size_t)b * TLEN + t] = tag;
        }
    }
}

// ---------------------------------------------------------------------------
extern "C" void kernel_launch(void* const* d_in, const int* in_sizes, int n_in,
                              void* d_out, int out_size, void* d_ws, size_t ws_size,
                              hipStream_t stream)
{
    (void)in_sizes; (void)n_in; (void)out_size;
    const int*   inputs     = (const int*)d_in[0];
    const float* emb        = (const float*)d_in[1];
    const float* W_ih_l0_f  = (const float*)d_in[2];
    const float* W_hh_l0_f  = (const float*)d_in[3];
    const float* b_ih_l0_f  = (const float*)d_in[4];
    const float* b_hh_l0_f  = (const float*)d_in[5];
    const float* W_ih_l0_b  = (const float*)d_in[6];
    const float* W_hh_l0_b  = (const float*)d_in[7];
    const float* b_ih_l0_b  = (const float*)d_in[8];
    const float* b_hh_l0_b  = (const float*)d_in[9];
    const float* W_ih_l1_f  = (const float*)d_in[10];
    const float* W_hh_l1_f  = (const float*)d_in[11];
    const float* b_ih_l1_f  = (const float*)d_in[12];
    const float* b_hh_l1_f  = (const float*)d_in[13];
    const float* W_ih_l1_b  = (const float*)d_in[14];
    const float* W_hh_l1_b  = (const float*)d_in[15];
    const float* b_ih_l1_b  = (const float*)d_in[16];
    const float* b_hh_l1_b  = (const float*)d_in[17];
    const float* W_out      = (const float*)d_in[18];
    const float* b_out      = (const float*)d_in[19];
    const float* start_tr   = (const float*)d_in[20];
    const float* end_tr     = (const float*)d_in[21];
    const float* trans      = (const float*)d_in[22];

    // ws: xbuf 64MB | gxA_f gxA_b gxB_f gxB_b (4 x C*256KB) | hbuf C*128KB |
    //     em_f 4MB | em_b 4MB | state 512KB | hxs 512KB
    const size_t XBUF = 67108864ull;
    const size_t PERC = 4ull * 262144 + 131072;          // 1.125 MB per C
    const size_t TAIL = 2ull * 4194304 + 524288 + 524288;
    int C = 8;
    for (int cand = TLEN; cand >= 8; cand >>= 1) {
        if (XBUF + (size_t)cand * PERC + TAIL <= ws_size) { C = cand; break; }
    }
    char* ws = (char*)d_ws;
    float* xbuf  = (float*)(ws);
    char*  p     = ws + XBUF;
    float* gxA_f = (float*)(p); p += (size_t)C * 262144;
    float* gxA_b = (float*)(p); p += (size_t)C * 262144;
    float* gxB_f = (float*)(p); p += (size_t)C * 262144;
    float* gxB_b = (float*)(p); p += (size_t)C * 262144;
    float* hbuf  = (float*)(p); p += (size_t)C * 131072;
    float* em_f  = (float*)(p); p += 4194304;
    float* em_b  = (float*)(p); p += 4194304;
    float* state = (float*)(p); p += 524288;
    uint64_t* hxs = (uint64_t*)(p);
    int* outi = (int*)d_out;

    const int nc = TLEN / C;
    const int nmt = C / 2;          // 128-row m-tiles per chunk
    const int NG = nmt * 16;        // gemm blocks (both dirs)
    const int NL = 256;             // lstm blocks (4 per cluster x 64)
    float* gxf[2] = { gxA_f, gxB_f };
    float* gxb[2] = { gxA_b, gxB_b };

    hipMemsetAsync(hxs, 0, 524288, stream);   // stamp 0 everywhere
    unsigned fbase = 0;

    // ----- layer 0 ----- (warmup gemm chunk 0, then fused chain)
    lstm_fused<EDIM, true, true><<<NG, 512, 0, stream>>>(
        gxA_f, gxA_b, W_hh_l0_f, W_hh_l0_b, xbuf, nullptr, state, hxs, 0,
        0, 0, C, 1, /*nlstm=*/0, nmt,
        emb, inputs, W_ih_l0_f, W_ih_l0_b,
        b_ih_l0_f, b_hh_l0_f, b_ih_l0_b, b_hh_l0_b,
        gxA_f, gxA_b, 0, TLEN - C, 0, 0);
    for (int c = 0; c < nc; ++c) {
        int cur = c & 1, nxt = cur ^ 1;
        int hasN = (c + 1 < nc);
        int t0f = c * C, t0b = TLEN - (c + 1) * C;
        int g0f = (c + 1) * C, g0b = TLEN - (c + 2) * C;
        lstm_fused<EDIM, true, true><<<NL + (hasN ? NG : 0), 512, 0, stream>>>(
            gxf[cur], gxb[cur], W_hh_l0_f, W_hh_l0_b, xbuf, nullptr, state,
            hxs, fbase, t0f, t0b, C, c == 0 ? 1 : 0, NL, nmt,
            emb, inputs, W_ih_l0_f, W_ih_l0_b,
            b_ih_l0_f, b_hh_l0_f, b_ih_l0_b, b_hh_l0_b,
            gxf[nxt], gxb[nxt], g0f, g0b, 0, 0);
        fbase += (unsigned)C;
    }
    // ----- layer 1 ----- (xbuf READ-ONLY; h -> hbuf -> em parts)
    lstm_fused<512, false, false><<<NG, 512, 0, stream>>>(
        gxA_f, gxA_b, W_hh_l1_f, W_hh_l1_b, nullptr, hbuf, state, hxs, 0,
        0, 0, C, 1, /*nlstm=*/0, nmt,
        xbuf, nullptr, W_ih_l1_f, W_ih_l1_b,
        b_ih_l1_f, b_hh_l1_f, b_ih_l1_b, b_hh_l1_b,
        gxA_f, gxA_b, 0, TLEN - C, 0, (TLEN - C) * BSZ);
    for (int c = 0; c < nc; ++c) {
        int cur = c & 1, nxt = cur ^ 1;
        int hasN = (c + 1 < nc);
        int t0f = c * C, t0b = TLEN - (c + 1) * C;
        int g0f = (c + 1) * C, g0b = TLEN - (c + 2) * C;
        lstm_fused<512, false, false><<<NL + (hasN ? NG : 0), 512, 0, stream>>>(
            gxf[cur], gxb[cur], W_hh_l1_f, W_hh_l1_b, nullptr, hbuf, state,
            hxs, fbase, t0f, t0b, C, c == 0 ? 1 : 0, NL, nmt,
            xbuf, nullptr, W_ih_l1_f, W_ih_l1_b,
            b_ih_l1_f, b_hh_l1_f, b_ih_l1_b, b_hh_l1_b,
            gxf[nxt], gxb[nxt], g0f, g0b, g0f * BSZ, g0b * BSZ);
        fbase += (unsigned)C;
        dim3 ge(C * 8, 2);
        emis_part<<<ge, 256, 0, stream>>>(hbuf, W_out, em_f, em_b, t0f, t0b, C);
    }

    viterbi<<<64, 64, 0, stream>>>(em_f, em_b, b_out, start_tr, end_tr, trans,
                                   outi);
}